// Round 8
// baseline (206.366 us; speedup 1.0000x reference)
//
#include <hip/hip_runtime.h>
#include <hip/hip_bf16.h>

// SparseToDense: scatter features [N,32] into dense [B=4, C=32, D=64, H=64, W=64].
// flat_idx (int32 on device) indexes B*D*H*W sites; output is NCDHW. DHW = 2^18.
//
// Strategy: invert the scatter via per-site chains -> no float atomics, output
// written densely, coalesced, exactly once (no zero-fill pass).
//   R6: nt LOADS regressed (extra 16B no-allocate requests) -> cached loads.
//   R7: pair-split + nt stores == R4 baseline (204 us); gather ~55-60 us vs
//       ~32 us byte floor -> latency/MLP-bound, not byte-bound.
//   R8: quad-tiled gather: 4 sites x 8 channels per thread.
//       - 4 head loads issued together -> 4 independent chains in flight (MLP)
//       - 8 x float4 nontemporal stores (4x256 B segments per wave-store)
//       - feats row = one 128 B line per lane-quad (q=0..3 read 32 B each)

#define DHW_LOG2 18
#define DHW (1 << DHW_LOG2)
#define C_CH 32
#define N_SITES_TOTAL (4 * DHW)   // B=4

typedef float floatx4 __attribute__((ext_vector_type(4)));

__global__ __launch_bounds__(256) void init_head_kernel(int* __restrict__ head, int n)
{
    int t = blockIdx.x * blockDim.x + threadIdx.x;
    if (t < n) head[t] = -1;
}

__global__ __launch_bounds__(256) void build_chains_kernel(
    const int* __restrict__ flat_idx,
    int* __restrict__ head,
    int* __restrict__ next,
    int n_active)
{
    int i = blockIdx.x * blockDim.x + threadIdx.x;
    if (i >= n_active) return;
    int s = flat_idx[i];
    int prev = atomicExch(&head[s], i);   // device-scope int atomic, 4 MB array
    next[i] = prev;
}

__global__ __launch_bounds__(256) void gather_kernel(
    const float* __restrict__ feats,
    const int* __restrict__ head,
    const int* __restrict__ next,
    float* __restrict__ out)
{
    int t = blockIdx.x * blockDim.x + threadIdx.x;   // N_SITES_TOTAL threads
    int g = t >> 2;          // site quad
    int q = t & 3;           // channel quarter: channels q*8 .. q*8+7
    int S0 = g << 2;         // first site of quad (quads never cross batch: DHW%4==0)
    int b  = S0 >> DHW_LOG2;
    int sp = S0 & (DHW - 1);

    float acc[8][4];         // [channel j within quarter][site s within quad]
    #pragma unroll
    for (int j = 0; j < 8; ++j)
        #pragma unroll
        for (int s = 0; s < 4; ++s) acc[j][s] = 0.f;

    // 4 independent chain heads issued back-to-back (MLP).
    int p0 = head[S0 + 0];
    int p1 = head[S0 + 1];
    int p2 = head[S0 + 2];
    int p3 = head[S0 + 3];

#define WALK(P, S)                                                              \
    while (P >= 0) {                                                            \
        const floatx4* row = (const floatx4*)(feats + (size_t)P * C_CH + q * 8);\
        int pn = next[P];                                                       \
        floatx4 r0 = row[0];  /* quad lanes cover the 128 B row contiguously */ \
        floatx4 r1 = row[1];                                                    \
        acc[0][S] += r0.x; acc[1][S] += r0.y; acc[2][S] += r0.z; acc[3][S] += r0.w; \
        acc[4][S] += r1.x; acc[5][S] += r1.y; acc[6][S] += r1.z; acc[7][S] += r1.w; \
        P = pn;                                                                 \
    }
    WALK(p0, 0)
    WALK(p1, 1)
    WALK(p2, 2)
    WALK(p3, 3)
#undef WALK

    // out[(b*32 + q*8 + j) << 18 | sp..sp+3] -- 16 B aligned (sp % 4 == 0).
    // Per wave-store: 4 contiguous 256 B segments (one per channel quarter).
    float* o = out + (((size_t)(b * C_CH + q * 8)) << DHW_LOG2) + sp;
    #pragma unroll
    for (int j = 0; j < 8; ++j) {
        floatx4 v = { acc[j][0], acc[j][1], acc[j][2], acc[j][3] };
        __builtin_nontemporal_store(v, (floatx4*)(o + ((size_t)j << DHW_LOG2)));
    }
}

// ---- fallback (R3 behavior) if workspace is too small ----
__global__ __launch_bounds__(256) void zero_kernel(float4* __restrict__ out, int n4)
{
    int t = blockIdx.x * blockDim.x + threadIdx.x;
    if (t < n4) out[t] = make_float4(0.f, 0.f, 0.f, 0.f);
}

__global__ __launch_bounds__(256) void scatter_atomic_kernel(
    const float* __restrict__ feats,
    const int* __restrict__ flat_idx,
    float* __restrict__ out,
    int n_active)
{
    int t = blockIdx.x * blockDim.x + threadIdx.x;
    int i = t >> 5, c = t & 31;
    if (i >= n_active) return;
    int s = flat_idx[i];
    atomicAdd(&out[(((size_t)(s >> DHW_LOG2) * C_CH + c) << DHW_LOG2) + (s & (DHW - 1))],
              feats[(size_t)i * C_CH + c]);
}

extern "C" void kernel_launch(void* const* d_in, const int* in_sizes, int n_in,
                              void* d_out, int out_size, void* d_ws, size_t ws_size,
                              hipStream_t stream) {
    const float* feats = (const float*)d_in[0];
    const int*   idx   = (const int*)d_in[1];
    float*       out   = (float*)d_out;
    int n_active = in_sizes[1];   // 400000

    size_t head_bytes = (size_t)N_SITES_TOTAL * sizeof(int);      // 4 MB
    size_t next_bytes = (size_t)n_active * sizeof(int);           // 1.6 MB

    if (ws_size >= head_bytes + next_bytes) {
        int* head = (int*)d_ws;
        int* next = (int*)((char*)d_ws + head_bytes);

        init_head_kernel<<<(N_SITES_TOTAL + 255) / 256, 256, 0, stream>>>(head, N_SITES_TOTAL);
        build_chains_kernel<<<(n_active + 255) / 256, 256, 0, stream>>>(idx, head, next, n_active);
        // one thread per site, organized as site-quads x channel-quarters
        gather_kernel<<<N_SITES_TOTAL / 256, 256, 0, stream>>>(feats, head, next, out);
    } else {
        // fallback: R3 atomic path
        int n4 = out_size >> 2;
        zero_kernel<<<(n4 + 255) / 256, 256, 0, stream>>>((float4*)out, n4);
        int total = n_active * C_CH;
        scatter_atomic_kernel<<<(total + 255) / 256, 256, 0, stream>>>(feats, idx, out, n_active);
    }
}